// Round 1
// baseline (1922.137 us; speedup 1.0000x reference)
//
#include <hip/hip_runtime.h>
#include <math.h>

// Problem constants
#define L_SEQ 8192
#define H_DIM 1024
#define N_DIM 1024
#define NCHUNK 64
#define CHUNK (L_SEQ / NCHUNK)   // 128

// ---------------------------------------------------------------------------
// Precompute Lambda = exp(-exp(nu_log) + i*exp(theta_log))
// ---------------------------------------------------------------------------
__global__ void lru_lambda(const float* __restrict__ nu_log,
                           const float* __restrict__ theta_log,
                           float* __restrict__ Lr, float* __restrict__ Li) {
    int n = blockIdx.x * 256 + threadIdx.x;
    if (n >= N_DIM) return;
    float nu  = expf(nu_log[n]);
    float th  = expf(theta_log[n]);
    float mag = expf(-nu);
    Lr[n] = mag * cosf(th);
    Li[n] = mag * sinf(th);
}

// ---------------------------------------------------------------------------
// B_norm = (B_real + i B_imag) * exp(i * gamma_log)   (N, H)
// ---------------------------------------------------------------------------
__global__ void lru_bnorm(const float* __restrict__ B_real,
                          const float* __restrict__ B_imag,
                          const float* __restrict__ gamma_log,
                          float* __restrict__ Bnr, float* __restrict__ Bni) {
    int idx = blockIdx.x * 256 + threadIdx.x;       // over N*H
    int n = idx >> 10;                              // H == 1024
    float g = gamma_log[n];
    float egr = cosf(g), egi = sinf(g);
    float br = B_real[idx], bi = B_imag[idx];
    Bnr[idx] = br * egr - bi * egi;
    Bni[idx] = br * egi + bi * egr;
}

// ---------------------------------------------------------------------------
// GEMM1: Bu[l,n] = sum_h u[l,h] * B_norm[n,h]   (complex x complex)
// A (L,H) row-major k-contig, B (N,H) row-major k-contig  ->  A*B^T form.
// 64x64 tile, BK=16, 256 threads, 4x4 outputs/thread.
// LDS staged transposed [k][m] with +4 pad: fragment reads are ds_read_b128,
// conflict-free (A frag broadcasts, B frag covers 64 consecutive floats).
// ---------------------------------------------------------------------------
__global__ __launch_bounds__(256) void lru_gemm1(
    const float* __restrict__ Ar_g, const float* __restrict__ Ai_g,
    const float* __restrict__ Br_g, const float* __restrict__ Bi_g,
    float* __restrict__ Or_g, float* __restrict__ Oi_g) {
    __shared__ float Asr[16][68], Asi[16][68], Bsr[16][68], Bsi[16][68];
    const int tid = threadIdx.x;
    const int bm = blockIdx.x * 64;   // L offset
    const int bn = blockIdx.y * 64;   // N offset
    const int ty = tid >> 4;          // 0..15 -> row group
    const int tx = tid & 15;          // 0..15 -> col group
    const int lr = tid >> 2;          // 0..63 staging row
    const int lk = (tid & 3) << 2;    // 0,4,8,12 staging k

    float accr[4][4] = {{0.f}}, acci[4][4] = {{0.f}};

    const size_t a_base = (size_t)(bm + lr) * H_DIM + lk;
    const size_t b_base = (size_t)(bn + lr) * H_DIM + lk;

    for (int k0 = 0; k0 < H_DIM; k0 += 16) {
        float4 ga_r = *reinterpret_cast<const float4*>(Ar_g + a_base + k0);
        float4 ga_i = *reinterpret_cast<const float4*>(Ai_g + a_base + k0);
        float4 gb_r = *reinterpret_cast<const float4*>(Br_g + b_base + k0);
        float4 gb_i = *reinterpret_cast<const float4*>(Bi_g + b_base + k0);
        __syncthreads();
        Asr[lk+0][lr] = ga_r.x; Asr[lk+1][lr] = ga_r.y; Asr[lk+2][lr] = ga_r.z; Asr[lk+3][lr] = ga_r.w;
        Asi[lk+0][lr] = ga_i.x; Asi[lk+1][lr] = ga_i.y; Asi[lk+2][lr] = ga_i.z; Asi[lk+3][lr] = ga_i.w;
        Bsr[lk+0][lr] = gb_r.x; Bsr[lk+1][lr] = gb_r.y; Bsr[lk+2][lr] = gb_r.z; Bsr[lk+3][lr] = gb_r.w;
        Bsi[lk+0][lr] = gb_i.x; Bsi[lk+1][lr] = gb_i.y; Bsi[lk+2][lr] = gb_i.z; Bsi[lk+3][lr] = gb_i.w;
        __syncthreads();
#pragma unroll
        for (int kk = 0; kk < 16; ++kk) {
            float4 far = *reinterpret_cast<const float4*>(&Asr[kk][ty << 2]);
            float4 fai = *reinterpret_cast<const float4*>(&Asi[kk][ty << 2]);
            float4 fbr = *reinterpret_cast<const float4*>(&Bsr[kk][tx << 2]);
            float4 fbi = *reinterpret_cast<const float4*>(&Bsi[kk][tx << 2]);
            const float arv[4] = {far.x, far.y, far.z, far.w};
            const float aiv[4] = {fai.x, fai.y, fai.z, fai.w};
            const float brv[4] = {fbr.x, fbr.y, fbr.z, fbr.w};
            const float biv[4] = {fbi.x, fbi.y, fbi.z, fbi.w};
#pragma unroll
            for (int i = 0; i < 4; ++i)
#pragma unroll
                for (int j = 0; j < 4; ++j) {
                    accr[i][j] += arv[i] * brv[j] - aiv[i] * biv[j];
                    acci[i][j] += arv[i] * biv[j] + aiv[i] * brv[j];
                }
        }
    }
#pragma unroll
    for (int i = 0; i < 4; ++i) {
        int row = bm + (ty << 2) + i;
        size_t o = (size_t)row * N_DIM + bn + (tx << 2);
        float4 vr = make_float4(accr[i][0], accr[i][1], accr[i][2], accr[i][3]);
        float4 vi = make_float4(acci[i][0], acci[i][1], acci[i][2], acci[i][3]);
        *reinterpret_cast<float4*>(Or_g + o) = vr;
        *reinterpret_cast<float4*>(Oi_g + o) = vi;
    }
}

// ---------------------------------------------------------------------------
// Scan pass A: per-(channel, chunk) local scan, in-place over Bu.
// Also emits A_c = Lambda^CHUNK and b_c = local final state per chunk.
// Consecutive threads = consecutive channels -> coalesced.
// ---------------------------------------------------------------------------
__global__ void lru_scan_local(float* __restrict__ Bur, float* __restrict__ Bui,
                               const float* __restrict__ Lr, const float* __restrict__ Li,
                               float* __restrict__ Acr, float* __restrict__ Aci,
                               float* __restrict__ bcr, float* __restrict__ bci) {
    int n = blockIdx.y * 256 + threadIdx.x;
    int c = blockIdx.x;
    float lr = Lr[n], li = Li[n];
    float sr = 0.f, si = 0.f;           // running state (zero initial)
    float pr = 1.f, pi = 0.f;           // Lambda^j accumulator
    size_t base = (size_t)c * CHUNK * N_DIM + n;
    for (int j = 0; j < CHUNK; ++j) {
        size_t idx = base + (size_t)j * N_DIM;
        float br = Bur[idx], bi = Bui[idx];
        float nr = lr * sr - li * si + br;
        float ni = lr * si + li * sr + bi;
        sr = nr; si = ni;
        Bur[idx] = sr; Bui[idx] = si;
        float qr = lr * pr - li * pi;
        float qi = lr * pi + li * pr;
        pr = qr; pi = qi;
    }
    Acr[c * N_DIM + n] = pr; Aci[c * N_DIM + n] = pi;
    bcr[c * N_DIM + n] = sr; bci[c * N_DIM + n] = si;
}

// ---------------------------------------------------------------------------
// Scan pass B(mid): sequential scan over the NCHUNK chunk summaries,
// producing carry_in[c] = exact state entering chunk c.
// ---------------------------------------------------------------------------
__global__ void lru_scan_carry(const float* __restrict__ Acr, const float* __restrict__ Aci,
                               const float* __restrict__ bcr, const float* __restrict__ bci,
                               float* __restrict__ car, float* __restrict__ cai) {
    int n = blockIdx.x * 256 + threadIdx.x;
    float sr = 0.f, si = 0.f;
    for (int c = 0; c < NCHUNK; ++c) {
        car[c * N_DIM + n] = sr; cai[c * N_DIM + n] = si;
        float ar = Acr[c * N_DIM + n], ai = Aci[c * N_DIM + n];
        float nr = ar * sr - ai * si + bcr[c * N_DIM + n];
        float ni = ar * si + ai * sr + bci[c * N_DIM + n];
        sr = nr; si = ni;
    }
}

// ---------------------------------------------------------------------------
// Scan pass C: x[l0+j] += Lambda^(j+1) * carry_in   (chunks 1..NCHUNK-1)
// ---------------------------------------------------------------------------
__global__ void lru_scan_fix(float* __restrict__ Bur, float* __restrict__ Bui,
                             const float* __restrict__ Lr, const float* __restrict__ Li,
                             const float* __restrict__ car, const float* __restrict__ cai) {
    int n = blockIdx.y * 256 + threadIdx.x;
    int c = blockIdx.x + 1;
    float lr = Lr[n], li = Li[n];
    float cr = car[c * N_DIM + n], ci = cai[c * N_DIM + n];
    // p = Lambda * carry, then p *= Lambda each step
    float pr = lr * cr - li * ci;
    float pi = lr * ci + li * cr;
    size_t base = (size_t)c * CHUNK * N_DIM + n;
    for (int j = 0; j < CHUNK; ++j) {
        size_t idx = base + (size_t)j * N_DIM;
        Bur[idx] += pr;
        Bui[idx] += pi;
        float qr = lr * pr - li * pi;
        float qi = lr * pi + li * pr;
        pr = qr; pi = qi;
    }
}

// ---------------------------------------------------------------------------
// GEMM2: y[l,h] = sum_n (xr[l,n]*Cr[h,n] - xi[l,n]*Ci[h,n]) + D[h]*ur[l,h]
// Same tiling as GEMM1; single real output with fused D-term epilogue.
// ---------------------------------------------------------------------------
__global__ __launch_bounds__(256) void lru_gemm2(
    const float* __restrict__ Xr_g, const float* __restrict__ Xi_g,
    const float* __restrict__ Cr_g, const float* __restrict__ Ci_g,
    const float* __restrict__ D_g,  const float* __restrict__ Ur_g,
    float* __restrict__ Y_g) {
    __shared__ float Asr[16][68], Asi[16][68], Bsr[16][68], Bsi[16][68];
    const int tid = threadIdx.x;
    const int bm = blockIdx.x * 64;   // L offset
    const int bn = blockIdx.y * 64;   // H offset
    const int ty = tid >> 4;
    const int tx = tid & 15;
    const int lr = tid >> 2;
    const int lk = (tid & 3) << 2;

    float acc[4][4] = {{0.f}};

    const size_t a_base = (size_t)(bm + lr) * N_DIM + lk;
    const size_t b_base = (size_t)(bn + lr) * N_DIM + lk;

    for (int k0 = 0; k0 < N_DIM; k0 += 16) {
        float4 ga_r = *reinterpret_cast<const float4*>(Xr_g + a_base + k0);
        float4 ga_i = *reinterpret_cast<const float4*>(Xi_g + a_base + k0);
        float4 gb_r = *reinterpret_cast<const float4*>(Cr_g + b_base + k0);
        float4 gb_i = *reinterpret_cast<const float4*>(Ci_g + b_base + k0);
        __syncthreads();
        Asr[lk+0][lr] = ga_r.x; Asr[lk+1][lr] = ga_r.y; Asr[lk+2][lr] = ga_r.z; Asr[lk+3][lr] = ga_r.w;
        Asi[lk+0][lr] = ga_i.x; Asi[lk+1][lr] = ga_i.y; Asi[lk+2][lr] = ga_i.z; Asi[lk+3][lr] = ga_i.w;
        Bsr[lk+0][lr] = gb_r.x; Bsr[lk+1][lr] = gb_r.y; Bsr[lk+2][lr] = gb_r.z; Bsr[lk+3][lr] = gb_r.w;
        Bsi[lk+0][lr] = gb_i.x; Bsi[lk+1][lr] = gb_i.y; Bsi[lk+2][lr] = gb_i.z; Bsi[lk+3][lr] = gb_i.w;
        __syncthreads();
#pragma unroll
        for (int kk = 0; kk < 16; ++kk) {
            float4 far = *reinterpret_cast<const float4*>(&Asr[kk][ty << 2]);
            float4 fai = *reinterpret_cast<const float4*>(&Asi[kk][ty << 2]);
            float4 fbr = *reinterpret_cast<const float4*>(&Bsr[kk][tx << 2]);
            float4 fbi = *reinterpret_cast<const float4*>(&Bsi[kk][tx << 2]);
            const float xrv[4] = {far.x, far.y, far.z, far.w};
            const float xiv[4] = {fai.x, fai.y, fai.z, fai.w};
            const float crv[4] = {fbr.x, fbr.y, fbr.z, fbr.w};
            const float civ[4] = {fbi.x, fbi.y, fbi.z, fbi.w};
#pragma unroll
            for (int i = 0; i < 4; ++i)
#pragma unroll
                for (int j = 0; j < 4; ++j) {
                    acc[i][j] += xrv[i] * crv[j] - xiv[i] * civ[j];
                }
        }
    }
    const float4 dv = *reinterpret_cast<const float4*>(D_g + bn + (tx << 2));
#pragma unroll
    for (int i = 0; i < 4; ++i) {
        int row = bm + (ty << 2) + i;
        size_t o = (size_t)row * H_DIM + bn + (tx << 2);
        float4 uv = *reinterpret_cast<const float4*>(Ur_g + o);
        float4 out = make_float4(acc[i][0] + dv.x * uv.x,
                                 acc[i][1] + dv.y * uv.y,
                                 acc[i][2] + dv.z * uv.z,
                                 acc[i][3] + dv.w * uv.w);
        *reinterpret_cast<float4*>(Y_g + o) = out;
    }
}

// ---------------------------------------------------------------------------
// Launch
// ---------------------------------------------------------------------------
extern "C" void kernel_launch(void* const* d_in, const int* in_sizes, int n_in,
                              void* d_out, int out_size, void* d_ws, size_t ws_size,
                              hipStream_t stream) {
    const float* input_real = (const float*)d_in[0];
    const float* input_imag = (const float*)d_in[1];
    const float* nu_log     = (const float*)d_in[2];
    const float* theta_log  = (const float*)d_in[3];
    const float* B_real     = (const float*)d_in[4];
    const float* B_imag     = (const float*)d_in[5];
    const float* C_real     = (const float*)d_in[6];
    const float* C_imag     = (const float*)d_in[7];
    const float* D          = (const float*)d_in[8];
    const float* gamma_log  = (const float*)d_in[9];
    float* y = (float*)d_out;

    // Workspace layout (floats). Total ~76 MB.
    float* f   = (float*)d_ws;
    float* Lr  = f;
    float* Li  = Lr + N_DIM;
    float* Bnr = Li + N_DIM;                            // N*H
    float* Bni = Bnr + (size_t)N_DIM * H_DIM;
    float* Bur = Bni + (size_t)N_DIM * H_DIM;           // L*N (becomes x in-place)
    float* Bui = Bur + (size_t)L_SEQ * N_DIM;
    float* Acr = Bui + (size_t)L_SEQ * N_DIM;           // NCHUNK*N each
    float* Aci = Acr + NCHUNK * N_DIM;
    float* bcr = Aci + NCHUNK * N_DIM;
    float* bci = bcr + NCHUNK * N_DIM;
    float* car = bci + NCHUNK * N_DIM;
    float* cai = car + NCHUNK * N_DIM;

    lru_lambda<<<(N_DIM + 255) / 256, 256, 0, stream>>>(nu_log, theta_log, Lr, Li);
    lru_bnorm<<<(N_DIM * H_DIM) / 256, 256, 0, stream>>>(B_real, B_imag, gamma_log, Bnr, Bni);
    lru_gemm1<<<dim3(L_SEQ / 64, N_DIM / 64), 256, 0, stream>>>(
        input_real, input_imag, Bnr, Bni, Bur, Bui);
    lru_scan_local<<<dim3(NCHUNK, N_DIM / 256), 256, 0, stream>>>(
        Bur, Bui, Lr, Li, Acr, Aci, bcr, bci);
    lru_scan_carry<<<N_DIM / 256, 256, 0, stream>>>(Acr, Aci, bcr, bci, car, cai);
    lru_scan_fix<<<dim3(NCHUNK - 1, N_DIM / 256), 256, 0, stream>>>(
        Bur, Bui, Lr, Li, car, cai);
    lru_gemm2<<<dim3(L_SEQ / 64, H_DIM / 64), 256, 0, stream>>>(
        Bur, Bui, C_real, C_imag, D, input_real, y);
}

// Round 2
// 234.089 us; speedup vs baseline: 8.2112x; 8.2112x over previous
//
#include <hip/hip_runtime.h>
#include <math.h>

#define L_SEQ 8192
#define H_DIM 1024
#define N_DIM 1024
#define K2    2048          // packed K = 2*H = 2*N
#define NCHUNK 64
#define CHUNK 128

typedef unsigned short u16;
typedef __attribute__((ext_vector_type(8))) __bf16 bf16x8;
typedef __attribute__((ext_vector_type(4))) float  f32x4;

__device__ __forceinline__ u16 f2bf(float x) {
    unsigned int u = __float_as_uint(x);
    u = (u + 0x7fffu + ((u >> 16) & 1u)) >> 16;   // RNE
    return (u16)u;
}
__device__ __forceinline__ float bf2f(u16 h) {
    return __uint_as_float(((unsigned int)h) << 16);
}

__device__ __forceinline__ void gload_lds16(const void* g, void* s) {
    __builtin_amdgcn_global_load_lds(
        (const __attribute__((address_space(1))) unsigned int*)g,
        (__attribute__((address_space(3))) unsigned int*)s, 16, 0, 0);
}

// ---------------------------------------------------------------------------
// Lambda = exp(-exp(nu_log) + i*exp(theta_log))
// ---------------------------------------------------------------------------
__global__ void lru_lambda(const float* __restrict__ nu_log,
                           const float* __restrict__ theta_log,
                           float* __restrict__ Lr, float* __restrict__ Li) {
    int n = blockIdx.x * 256 + threadIdx.x;
    float nu  = expf(nu_log[n]);
    float th  = expf(theta_log[n]);
    float mag = expf(-nu);
    Lr[n] = mag * cosf(th);
    Li[n] = mag * sinf(th);
}

// ---------------------------------------------------------------------------
// Pack u -> A' bf16 [L][2H]: cols [0,1024)=u_r, [1024,2048)=u_i
// ---------------------------------------------------------------------------
__global__ void pack_u(const float* __restrict__ R, const float* __restrict__ I,
                       u16* __restrict__ A) {
    size_t t = (size_t)blockIdx.x * 256 + threadIdx.x;
    size_t base = t * 4;                      // over L*H
    int lrow = (int)(base >> 10);
    int h    = (int)(base & 1023);
    float4 r  = *reinterpret_cast<const float4*>(R + base);
    float4 im = *reinterpret_cast<const float4*>(I + base);
    u16* p0 = A + ((size_t)lrow << 11) + h;
    *reinterpret_cast<ushort4*>(p0) =
        make_ushort4(f2bf(r.x), f2bf(r.y), f2bf(r.z), f2bf(r.w));
    *reinterpret_cast<ushort4*>(p0 + 1024) =
        make_ushort4(f2bf(im.x), f2bf(im.y), f2bf(im.z), f2bf(im.w));
}

// ---------------------------------------------------------------------------
// B_norm pack -> Bp bf16 [2N][2H]:
//   row n      : [ bnr | -bni ]   (produces Bu_r in output col n)
//   row 1024+n : [ bni |  bnr ]   (produces Bu_i in output col 1024+n)
// ---------------------------------------------------------------------------
__global__ void bnorm_pack(const float* __restrict__ Br, const float* __restrict__ Bi,
                           const float* __restrict__ G, u16* __restrict__ Bp) {
    size_t t = (size_t)blockIdx.x * 256 + threadIdx.x;
    size_t base = t * 4;                      // over N*H
    int n = (int)(base >> 10);
    int h = (int)(base & 1023);
    float g = G[n];
    float sg, cg;
    sincosf(g, &sg, &cg);
    float4 br = *reinterpret_cast<const float4*>(Br + base);
    float4 bi = *reinterpret_cast<const float4*>(Bi + base);
    float nr0 = br.x * cg - bi.x * sg, ni0 = br.x * sg + bi.x * cg;
    float nr1 = br.y * cg - bi.y * sg, ni1 = br.y * sg + bi.y * cg;
    float nr2 = br.z * cg - bi.z * sg, ni2 = br.z * sg + bi.z * cg;
    float nr3 = br.w * cg - bi.w * sg, ni3 = br.w * sg + bi.w * cg;
    u16* row0 = Bp + (size_t)n * K2;
    u16* row1 = Bp + (size_t)(N_DIM + n) * K2;
    *reinterpret_cast<ushort4*>(row0 + h) =
        make_ushort4(f2bf(nr0), f2bf(nr1), f2bf(nr2), f2bf(nr3));
    *reinterpret_cast<ushort4*>(row0 + 1024 + h) =
        make_ushort4(f2bf(-ni0), f2bf(-ni1), f2bf(-ni2), f2bf(-ni3));
    *reinterpret_cast<ushort4*>(row1 + h) =
        make_ushort4(f2bf(ni0), f2bf(ni1), f2bf(ni2), f2bf(ni3));
    *reinterpret_cast<ushort4*>(row1 + 1024 + h) =
        make_ushort4(f2bf(nr0), f2bf(nr1), f2bf(nr2), f2bf(nr3));
}

// ---------------------------------------------------------------------------
// C pack -> Cp bf16 [H][2N]: row h = [ C_r[h][:] | -C_i[h][:] ]
// ---------------------------------------------------------------------------
__global__ void pack_C(const float* __restrict__ Cr, const float* __restrict__ Ci,
                       u16* __restrict__ Cp) {
    size_t t = (size_t)blockIdx.x * 256 + threadIdx.x;
    size_t base = t * 4;                      // over H*N
    int h = (int)(base >> 10);
    int n = (int)(base & 1023);
    float4 cr = *reinterpret_cast<const float4*>(Cr + base);
    float4 ci = *reinterpret_cast<const float4*>(Ci + base);
    u16* row = Cp + (size_t)h * K2;
    *reinterpret_cast<ushort4*>(row + n) =
        make_ushort4(f2bf(cr.x), f2bf(cr.y), f2bf(cr.z), f2bf(cr.w));
    *reinterpret_cast<ushort4*>(row + 1024 + n) =
        make_ushort4(f2bf(-ci.x), f2bf(-ci.y), f2bf(-ci.z), f2bf(-ci.w));
}

// ---------------------------------------------------------------------------
// bf16 MFMA GEMM, m97 structure: 128x128 tile, BK=32, 4 waves (2x2),
// 16x16x32 MFMA, global_load_lds width-16, XOR-swizzled LDS ((row&3)<<4)
// applied on the GLOBAL SOURCE side (linear LDS dest) + swizzled ds_read.
// A: [M][K] bf16 row-major, B: [Nout][K] bf16 row-major -> Out = A*B^T.
// EPI==0: store bf16 to OutB (ldo).  EPI==1: OutF = acc + Dv[col]*Ur[row,col].
// ---------------------------------------------------------------------------
template <int EPI>
__global__ __launch_bounds__(256) void mfma_gemm(
    const u16* __restrict__ A, const u16* __restrict__ B, int K,
    u16* __restrict__ OutB, float* __restrict__ OutF, int ldo,
    const float* __restrict__ Dv, const float* __restrict__ Ur) {
    __shared__ u16 Abuf[128 * 32];
    __shared__ u16 Bbuf[128 * 32];
    const int tid = threadIdx.x;
    const int l   = tid & 63;
    const int w   = tid >> 6;       // wave 0..3
    const int wm  = w >> 1, wn = w & 1;
    const long bm = (long)blockIdx.x * 128;
    const long bn = (long)blockIdx.y * 128;

    f32x4 acc[4][4];
#pragma unroll
    for (int i = 0; i < 4; ++i)
#pragma unroll
        for (int j = 0; j < 4; ++j) acc[i][j] = (f32x4){0.f, 0.f, 0.f, 0.f};

    // Staging geometry: instr p in {0,1}; wave w fills LDS chunk (p*4+w), 1KB.
    // lane l -> tile row (p*4+w)*16 + (l>>2), phys col byte (l&3)*16.
    // Source col byte = phys ^ ((row&3)<<4)  (inverse swizzle at the source).
    const int srow = l >> 2;
    const int scb  = (((l & 3) ^ (srow & 3)) << 4);
    const char* Ag0 = (const char*)(A + (size_t)(bm + w * 16 + srow) * K) + scb;
    const char* Ag1 = (const char*)(A + (size_t)(bm + 64 + w * 16 + srow) * K) + scb;
    const char* Bg0 = (const char*)(B + (size_t)(bn + w * 16 + srow) * K) + scb;
    const char* Bg1 = (const char*)(B + (size_t)(bn + 64 + w * 16 + srow) * K) + scb;
    u16* lA0 = Abuf + w * 512;
    u16* lA1 = Abuf + (4 + w) * 512;
    u16* lB0 = Bbuf + w * 512;
    u16* lB1 = Bbuf + (4 + w) * 512;

    // Fragment reads: lane l wants logical k-bytes (l>>4)*16 of row
    // (wq*64 + f*16 + (l&15)); physical col = logical ^ ((row&3)<<4), row&3==l&3.
    const int fcb = ((((l >> 4) ^ l) & 3) << 4);
    const int ra  = wm * 64 + (l & 15);
    const int rb  = wn * 64 + (l & 15);

    for (int k0 = 0; k0 < K; k0 += 32) {
        gload_lds16(Ag0 + (size_t)2 * k0, lA0);
        gload_lds16(Ag1 + (size_t)2 * k0, lA1);
        gload_lds16(Bg0 + (size_t)2 * k0, lB0);
        gload_lds16(Bg1 + (size_t)2 * k0, lB1);
        __syncthreads();                       // drains vmcnt: tiles resident
        bf16x8 af[4], bg[4];
#pragma unroll
        for (int mi = 0; mi < 4; ++mi)
            af[mi] = *reinterpret_cast<const bf16x8*>(
                (const char*)Abuf + (ra + mi * 16) * 64 + fcb);
#pragma unroll
        for (int ni = 0; ni < 4; ++ni)
            bg[ni] = *reinterpret_cast<const bf16x8*>(
                (const char*)Bbuf + (rb + ni * 16) * 64 + fcb);
#pragma unroll
        for (int mi = 0; mi < 4; ++mi)
#pragma unroll
            for (int ni = 0; ni < 4; ++ni)
                acc[mi][ni] = __builtin_amdgcn_mfma_f32_16x16x32_bf16(
                    af[mi], bg[ni], acc[mi][ni], 0, 0, 0);
        __syncthreads();                       // all reads done before restage
    }

    // C/D layout (m89-verified): col = lane&15, row = (lane>>4)*4 + reg
#pragma unroll
    for (int mi = 0; mi < 4; ++mi) {
        const long row0 = bm + wm * 64 + mi * 16 + ((l >> 4) << 2);
#pragma unroll
        for (int ni = 0; ni < 4; ++ni) {
            const long col = bn + wn * 64 + ni * 16 + (l & 15);
            if (EPI == 0) {
#pragma unroll
                for (int r = 0; r < 4; ++r)
                    OutB[(size_t)(row0 + r) * ldo + col] = f2bf(acc[mi][ni][r]);
            } else {
                const float d = Dv[col];
#pragma unroll
                for (int r = 0; r < 4; ++r) {
                    size_t o = (size_t)(row0 + r) * ldo + col;
                    OutF[o] = acc[mi][ni][r] + d * Ur[o];
                }
            }
        }
    }
}

// ---------------------------------------------------------------------------
// Scan pass A: per-(chunk, channel) local scan in fp32 state over bf16 X,
// in-place; emits Lambda^CHUNK and the local final state per chunk (fp32).
// X layout: [L][2048], col n = real, col 1024+n = imag.
// ---------------------------------------------------------------------------
__global__ void scan_local(u16* __restrict__ X,
                           const float* __restrict__ Lr, const float* __restrict__ Li,
                           float* __restrict__ Acr, float* __restrict__ Aci,
                           float* __restrict__ bcr, float* __restrict__ bci) {
    int n = blockIdx.y * 256 + threadIdx.x;   // 0..1023
    int c = blockIdx.x;
    float lr = Lr[n], li = Li[n];
    float sr = 0.f, si = 0.f, pr = 1.f, pi = 0.f;
    size_t base = (size_t)c * CHUNK * K2 + n;
    for (int j = 0; j < CHUNK; ++j) {
        size_t idx = base + (size_t)j * K2;
        float br = bf2f(X[idx]), bi = bf2f(X[idx + 1024]);
        float nr = lr * sr - li * si + br;
        float ni = lr * si + li * sr + bi;
        sr = nr; si = ni;
        X[idx] = f2bf(sr); X[idx + 1024] = f2bf(si);
        float qr = lr * pr - li * pi;
        float qi = lr * pi + li * pr;
        pr = qr; pi = qi;
    }
    Acr[c * N_DIM + n] = pr; Aci[c * N_DIM + n] = pi;
    bcr[c * N_DIM + n] = sr; bci[c * N_DIM + n] = si;
}

// ---------------------------------------------------------------------------
// Scan pass B: sequential scan over NCHUNK chunk summaries (fp32).
// ---------------------------------------------------------------------------
__global__ void scan_carry(const float* __restrict__ Acr, const float* __restrict__ Aci,
                           const float* __restrict__ bcr, const float* __restrict__ bci,
                           float* __restrict__ car, float* __restrict__ cai) {
    int n = blockIdx.x * 256 + threadIdx.x;
    float sr = 0.f, si = 0.f;
    for (int c = 0; c < NCHUNK; ++c) {
        car[c * N_DIM + n] = sr; cai[c * N_DIM + n] = si;
        float ar = Acr[c * N_DIM + n], ai = Aci[c * N_DIM + n];
        float nr = ar * sr - ai * si + bcr[c * N_DIM + n];
        float ni = ar * si + ai * sr + bci[c * N_DIM + n];
        sr = nr; si = ni;
    }
}

// ---------------------------------------------------------------------------
// Scan pass C: X[c*CHUNK+j] += Lambda^(j+1) * carry_in[c]   (bf16 RMW)
// ---------------------------------------------------------------------------
__global__ void scan_fix(u16* __restrict__ X,
                         const float* __restrict__ Lr, const float* __restrict__ Li,
                         const float* __restrict__ car, const float* __restrict__ cai) {
    int n = blockIdx.y * 256 + threadIdx.x;
    int c = blockIdx.x + 1;
    float lr = Lr[n], li = Li[n];
    float cr = car[c * N_DIM + n], ci = cai[c * N_DIM + n];
    float pr = lr * cr - li * ci;
    float pi = lr * ci + li * cr;
    size_t base = (size_t)c * CHUNK * K2 + n;
    for (int j = 0; j < CHUNK; ++j) {
        size_t idx = base + (size_t)j * K2;
        X[idx]        = f2bf(bf2f(X[idx]) + pr);
        X[idx + 1024] = f2bf(bf2f(X[idx + 1024]) + pi);
        float qr = lr * pr - li * pi;
        float qi = lr * pi + li * pr;
        pr = qr; pi = qi;
    }
}

// ---------------------------------------------------------------------------
// Launch
// ---------------------------------------------------------------------------
extern "C" void kernel_launch(void* const* d_in, const int* in_sizes, int n_in,
                              void* d_out, int out_size, void* d_ws, size_t ws_size,
                              hipStream_t stream) {
    (void)in_sizes; (void)n_in; (void)out_size; (void)ws_size;
    const float* input_real = (const float*)d_in[0];
    const float* input_imag = (const float*)d_in[1];
    const float* nu_log     = (const float*)d_in[2];
    const float* theta_log  = (const float*)d_in[3];
    const float* B_real     = (const float*)d_in[4];
    const float* B_imag     = (const float*)d_in[5];
    const float* C_real     = (const float*)d_in[6];
    const float* C_imag     = (const float*)d_in[7];
    const float* D          = (const float*)d_in[8];
    const float* gamma_log  = (const float*)d_in[9];
    float* y = (float*)d_out;

    // Workspace layout (bytes):
    // [0, 4K)            Lr          [4K, 8K)   Li
    // [8K, 8K+1.5M)      Acr/Aci/bcr/bci/car/cai (6 x 256KB)
    // [2M, 34M)          A' bf16 [8192][2048]  (Cp aliases its first 4MB)
    // [34M, 42M)         Bp bf16 [2048][2048]
    // [42M, 74M)         X  bf16 [8192][2048]  (Bu -> x in place)
    char* ws = (char*)d_ws;
    float* Lr  = (float*)(ws);
    float* Li  = (float*)(ws + (4 << 10));
    float* Acr = (float*)(ws + (8 << 10));
    float* Aci = Acr + NCHUNK * N_DIM;
    float* bcr = Aci + NCHUNK * N_DIM;
    float* bci = bcr + NCHUNK * N_DIM;
    float* car = bci + NCHUNK * N_DIM;
    float* cai = car + NCHUNK * N_DIM;
    u16* Ap = (u16*)(ws + ((size_t)2 << 20));
    u16* Cp = Ap;                                   // alias: used only after gemm1
    u16* Bp = (u16*)(ws + ((size_t)34 << 20));
    u16* X  = (u16*)(ws + ((size_t)42 << 20));

    lru_lambda<<<N_DIM / 256, 256, 0, stream>>>(nu_log, theta_log, Lr, Li);
    pack_u<<<(L_SEQ * H_DIM / 4) / 256, 256, 0, stream>>>(input_real, input_imag, Ap);
    bnorm_pack<<<(N_DIM * H_DIM / 4) / 256, 256, 0, stream>>>(B_real, B_imag, gamma_log, Bp);
    mfma_gemm<0><<<dim3(L_SEQ / 128, K2 / 128), 256, 0, stream>>>(
        Ap, Bp, K2, X, nullptr, K2, nullptr, nullptr);
    scan_local<<<dim3(NCHUNK, N_DIM / 256), 256, 0, stream>>>(X, Lr, Li, Acr, Aci, bcr, bci);
    scan_carry<<<N_DIM / 256, 256, 0, stream>>>(Acr, Aci, bcr, bci, car, cai);
    scan_fix<<<dim3(NCHUNK - 1, N_DIM / 256), 256, 0, stream>>>(X, Lr, Li, car, cai);
    pack_C<<<(H_DIM * N_DIM / 4) / 256, 256, 0, stream>>>(C_real, C_imag, Cp);
    mfma_gemm<1><<<dim3(L_SEQ / 128, H_DIM / 128), 256, 0, stream>>>(
        X, Cp, K2, nullptr, y, H_DIM, D, input_real);
}